// Round 1
// baseline (272.936 us; speedup 1.0000x reference)
//
#include <hip/hip_runtime.h>

#define N 4096
#define F 64
#define BZ 4
#define NC 65           // components: 64 features + 1 (constant 1 -> denominator)
#define NROWS (N + 1)   // prefix/suffix rows 0..N inclusive

// ---------------------------------------------------------------------------
// Kernel A: k[b][i] = x[b,i,:]·wk ; q[b][i] = x[b,i,:]·wq
// One wave per row; lane = feature. Coalesced 256B row loads.
// ---------------------------------------------------------------------------
__global__ __launch_bounds__(256) void kq_kernel(
        const float* __restrict__ x, const float* __restrict__ wk,
        const float* __restrict__ wq, float* __restrict__ kq) {
    int wave = blockIdx.x * 4 + (threadIdx.x >> 6);
    int lane = threadIdx.x & 63;
    int b = wave >> 12;        // wave / 4096
    int i = wave & (N - 1);
    float xv = x[((size_t)(b * N + i)) * F + lane];
    float kk = xv * wk[lane];
    float qq = xv * wq[lane];
    for (int off = 32; off > 0; off >>= 1) {
        kk += __shfl_down(kk, off, 64);
        qq += __shfl_down(qq, off, 64);
    }
    if (lane == 0) {
        kq[b * N + i] = kk;            // k block
        kq[BZ * N + b * N + i] = qq;   // q block
    }
}

// ---------------------------------------------------------------------------
// Kernel B+C: per batch (grid=BZ, 1024 threads):
//   1) bitonic sort (q, idx) ascending in LDS
//   2) chunk partial sums (64 chunks of 64) of e^{q-Qmax}*xt and e^{0.2(q-Qmax)}*xt
//   3) wave0 scans chunk totals (suffix for kind1, prefix for kind2)
//   4) write full positional SUF/PRE arrays [NROWS][NC] to ws
// LDS: 16K(qs) + 8K(ids) + 2*16.9K(tot) = 58.5 KB < 64 KB static limit.
// ---------------------------------------------------------------------------
__global__ __launch_bounds__(1024) void sort_scan_kernel(
        const float* __restrict__ x, const float* __restrict__ ws_q,
        float* __restrict__ q_sorted, float* __restrict__ SUF,
        float* __restrict__ PRE) {
    __shared__ float qs[N];
    __shared__ unsigned short ids[N];
    __shared__ float tot1[64][66];   // e^{q-Qmax} chunk sums -> exclusive suffix
    __shared__ float tot2[64][66];   // e^{0.2(q-Qmax)} chunk sums -> exclusive prefix

    int b = blockIdx.x;
    int tid = threadIdx.x;

    for (int t = tid; t < N; t += 1024) {
        qs[t] = ws_q[b * N + t];
        ids[t] = (unsigned short)t;
    }
    __syncthreads();

    // bitonic sort ascending on (qs, ids)
    for (int k = 2; k <= N; k <<= 1) {
        for (int j = k >> 1; j > 0; j >>= 1) {
            for (int i = tid; i < N; i += 1024) {
                int ixj = i ^ j;
                if (ixj > i) {
                    float a = qs[i], c = qs[ixj];
                    bool up = ((i & k) == 0);
                    if (up ? (a > c) : (a < c)) {
                        qs[i] = c; qs[ixj] = a;
                        unsigned short t0 = ids[i]; ids[i] = ids[ixj]; ids[ixj] = t0;
                    }
                }
            }
            __syncthreads();
        }
    }

    // publish sorted q for kernel D's binary search
    for (int t = tid; t < N; t += 1024) q_sorted[b * N + t] = qs[t];

    float Qmax = qs[N - 1];
    const float* xb = x + (size_t)b * N * F;
    int wave = tid >> 6, lane = tid & 63;

    // phase 1: chunk totals
    for (int c = wave; c < 64; c += 16) {
        float a1 = 0.f, a2 = 0.f, s1 = 0.f, s2 = 0.f;
        for (int r = 0; r < 64; ++r) {
            int t = c * 64 + r;
            float qv = qs[t];
            int id = ids[t];
            float e1 = __expf(qv - Qmax);
            float e2 = __expf(0.2f * (qv - Qmax));
            float xv = xb[(size_t)id * F + lane];
            a1 += e1 * xv; a2 += e2 * xv; s1 += e1; s2 += e2;
        }
        tot1[c][lane] = a1; tot2[c][lane] = a2;
        if (lane == 0) { tot1[c][64] = s1; tot2[c][64] = s2; }
    }
    __syncthreads();

    // phase 2: scan chunk totals in place (wave 0); write boundary row t=N
    if (wave == 0) {
        float run1 = 0.f;
        for (int c = 63; c >= 0; --c) { float t = tot1[c][lane]; tot1[c][lane] = run1; run1 += t; }
        SUF[((size_t)b * NROWS + N) * NC + lane] = 0.f;
        float run2 = 0.f;
        for (int c = 0; c < 64; ++c) { float t = tot2[c][lane]; tot2[c][lane] = run2; run2 += t; }
        PRE[((size_t)b * NROWS + N) * NC + lane] = run2;
        if (lane == 0) {
            float r1 = 0.f;
            for (int c = 63; c >= 0; --c) { float t = tot1[c][64]; tot1[c][64] = r1; r1 += t; }
            SUF[((size_t)b * NROWS + N) * NC + 64] = 0.f;
            float r2 = 0.f;
            for (int c = 0; c < 64; ++c) { float t = tot2[c][64]; tot2[c][64] = r2; r2 += t; }
            PRE[((size_t)b * NROWS + N) * NC + 64] = r2;
        }
    }
    __syncthreads();

    // phase 3: positional arrays.
    // SUF[t] = sum over sorted s>=t of e^{q_s-Qmax} * xt  (inclusive, reverse walk)
    // PRE[t] = sum over sorted s< t of e^{0.2(q_s-Qmax)} * xt (exclusive, fwd walk)
    for (int c = wave; c < 64; c += 16) {
        float run1 = tot1[c][lane];
        float run1s = tot1[c][64];
        for (int r = 63; r >= 0; --r) {
            int t = c * 64 + r;
            float qv = qs[t]; int id = ids[t];
            float e1 = __expf(qv - Qmax);
            float xv = xb[(size_t)id * F + lane];
            run1 += e1 * xv;
            run1s += e1;
            size_t row = ((size_t)b * NROWS + t) * NC;
            SUF[row + lane] = run1;
            if (lane == 0) SUF[row + 64] = run1s;
        }
        float run2 = tot2[c][lane];
        float run2s = tot2[c][64];
        for (int r = 0; r < 64; ++r) {
            int t = c * 64 + r;
            size_t row = ((size_t)b * NROWS + t) * NC;
            PRE[row + lane] = run2;
            if (lane == 0) PRE[row + 64] = run2s;
            float qv = qs[t]; int id = ids[t];
            float e2 = __expf(0.2f * (qv - Qmax));
            float xv = xb[(size_t)id * F + lane];
            run2 += e2 * xv;
            run2s += e2;
        }
    }
}

// ---------------------------------------------------------------------------
// Kernel D: per 64-row tile: p_i = lower_bound(q_sorted, -k_i);
// out[b,f,i] = (c1*SUF[p][f] + c2*PRE[p][f]) / (c1*SUF[p][64] + c2*PRE[p][64])
// with u = k_i + Qmax, M = max(u, 0.2u), c1 = e^{u-M}, c2 = e^{0.2u-M}.
// LDS transpose so final stores are coalesced along i.
// ---------------------------------------------------------------------------
__global__ __launch_bounds__(256) void out_kernel(
        const float* __restrict__ kws, const float* __restrict__ q_sorted,
        const float* __restrict__ SUF, const float* __restrict__ PRE,
        float* __restrict__ out) {
    __shared__ int pA[64];
    __shared__ float c1A[64], c2A[64], rdA[64];
    __shared__ float tile[64 * 65];

    int b = blockIdx.x >> 6;
    int i0 = (blockIdx.x & 63) * 64;
    int tid = threadIdx.x;
    const float* qsb = q_sorted + b * N;

    if (tid < 64) {
        int i = i0 + tid;
        float kk = kws[b * N + i];
        float theta = -kk;
        int lo = 0, hi = N;
        while (lo < hi) {
            int mid = (lo + hi) >> 1;
            if (qsb[mid] < theta) lo = mid + 1; else hi = mid;
        }
        int p = lo;
        float Qmax = qsb[N - 1];
        float u = kk + Qmax;
        float M = fmaxf(u, 0.2f * u);
        float c1 = __expf(u - M);
        float c2 = __expf(0.2f * u - M);
        size_t row = ((size_t)b * NROWS + p) * NC;
        float denom = c1 * SUF[row + 64] + c2 * PRE[row + 64];
        pA[tid] = p; c1A[tid] = c1; c2A[tid] = c2; rdA[tid] = 1.0f / denom;
    }
    __syncthreads();

    int f = tid & 63;
    int sub = tid >> 6;   // 0..3
    for (int rep = 0; rep < 16; ++rep) {
        int ii = rep * 4 + sub;            // fixed per wave -> coalesced SUF/PRE row reads
        int p = pA[ii];
        size_t row = ((size_t)b * NROWS + p) * NC;
        float val = (c1A[ii] * SUF[row + f] + c2A[ii] * PRE[row + f]) * rdA[ii];
        tile[f * 65 + ii] = val;
    }
    __syncthreads();
    for (int rep = 0; rep < 16; ++rep) {
        int ff = rep * 4 + sub;            // fixed per wave
        int ii = tid & 63;                 // varies -> coalesced 256B stores
        out[((size_t)(b * F + ff)) * N + i0 + ii] = tile[ff * 65 + ii];
    }
}

// ---------------------------------------------------------------------------
extern "C" void kernel_launch(void* const* d_in, const int* in_sizes, int n_in,
                              void* d_out, int out_size, void* d_ws, size_t ws_size,
                              hipStream_t stream) {
    const float* x  = (const float*)d_in[0];
    const float* wk = (const float*)d_in[1];
    const float* wq = (const float*)d_in[2];
    float* out = (float*)d_out;

    // ws layout (floats): k[BZ*N] | q[BZ*N] | q_sorted[BZ*N] | SUF[BZ*NROWS*NC] | PRE[...]
    float* ws = (float*)d_ws;
    float* kq = ws;
    float* q_sorted = ws + 2 * BZ * N;
    float* SUF = ws + 3 * BZ * N;
    float* PRE = SUF + (size_t)BZ * NROWS * NC;

    kq_kernel<<<BZ * N / 4, 256, 0, stream>>>(x, wk, wq, kq);
    sort_scan_kernel<<<BZ, 1024, 0, stream>>>(x, kq + BZ * N, q_sorted, SUF, PRE);
    out_kernel<<<BZ * 64, 256, 0, stream>>>(kq, q_sorted, SUF, PRE, out);
}

// Round 2
// 139.771 us; speedup vs baseline: 1.9527x; 1.9527x over previous
//
#include <hip/hip_runtime.h>

#define N 4096
#define F 64
#define BZ 4
#define NCH 256          // chunks per batch
#define RPC 16           // sorted rows per chunk
#define NC 65            // 64 features + 1 denominator component

// ---------------------------------------------------------------------------
// K1: k[b][i] = x[b,i,:]·wk ; q[b][i] = x[b,i,:]·wq.  Wave per row.
// ---------------------------------------------------------------------------
__global__ __launch_bounds__(256) void kq_kernel(
        const float* __restrict__ x, const float* __restrict__ wk,
        const float* __restrict__ wq, float* __restrict__ kq) {
    int wave = blockIdx.x * 4 + (threadIdx.x >> 6);
    int lane = threadIdx.x & 63;
    int b = wave >> 12;
    int i = wave & (N - 1);
    float xv = x[((size_t)(b * N + i)) * F + lane];
    float kk = xv * wk[lane];
    float qq = xv * wq[lane];
    for (int off = 32; off > 0; off >>= 1) {
        kk += __shfl_down(kk, off, 64);
        qq += __shfl_down(qq, off, 64);
    }
    if (lane == 0) {
        kq[b * N + i] = kk;            // k block
        kq[BZ * N + b * N + i] = qq;   // q block
    }
}

// ---------------------------------------------------------------------------
// K2: counting rank-sort + split points.
// grid BZ*64 blocks x 1024 threads. Block owns 64 j's; 16 parts of 256 q's.
//   rank_j = #{s : q_s < q_j  ||  (q_s == q_j && s < j)}   (exact permutation)
//   p_j    = #{s : q_s < -k_j}                             (leaky-relu split)
// Scatter: q_sorted[rank]=q_j, id_sorted[rank]=j.
// ---------------------------------------------------------------------------
__global__ __launch_bounds__(1024) void rank_kernel(
        const float* __restrict__ kq, float* __restrict__ q_sorted,
        int* __restrict__ id_sorted, int* __restrict__ p_arr) {
    __shared__ float qs[N];
    __shared__ unsigned short pc[16][64];
    __shared__ unsigned short pc2[16][64];
    int b = blockIdx.x >> 6;
    int tid = threadIdx.x;
    const float* qb = kq + BZ * N + b * N;
    for (int t = tid; t < N; t += 1024) qs[t] = qb[t];
    __syncthreads();

    int jl = tid & 63, part = tid >> 6;
    int j = (blockIdx.x & 63) * 64 + jl;
    float qj = qs[j];
    float theta = -kq[b * N + j];
    int cnt = 0, cnt2 = 0;
    int s0 = part * 256;
#pragma unroll 8
    for (int s = s0; s < s0 + 256; ++s) {
        float v = qs[s];
        cnt  += (int)((v < qj) | ((v == qj) & (s < j)));
        cnt2 += (int)(v < theta);
    }
    pc[part][jl] = (unsigned short)cnt;
    pc2[part][jl] = (unsigned short)cnt2;
    __syncthreads();

    if (part == 0) {
        int r = 0, p = 0;
#pragma unroll
        for (int pp = 0; pp < 16; ++pp) { r += pc[pp][jl]; p += pc2[pp][jl]; }
        q_sorted[b * N + r] = qj;
        id_sorted[b * N + r] = j;
        p_arr[b * N + j] = p;
    }
}

// ---------------------------------------------------------------------------
// K3: per-chunk totals. grid BZ*64 x 256 (wave per chunk of 16 sorted rows).
// tot1[b][c][0..63] = sum e^{q-Qmax} x[id][f],  [64] = sum e^{q-Qmax}
// tot2: same with exponent 0.2*(q-Qmax).
// ---------------------------------------------------------------------------
__global__ __launch_bounds__(256) void chunk_kernel(
        const float* __restrict__ x, const float* __restrict__ q_sorted,
        const int* __restrict__ id_sorted, float* __restrict__ tot1,
        float* __restrict__ tot2) {
    int b = blockIdx.x >> 6;
    int wave = threadIdx.x >> 6, lane = threadIdx.x & 63;
    int c = (blockIdx.x & 63) * 4 + wave;
    const float* qsb = q_sorted + b * N;
    const int* idb = id_sorted + b * N;
    const float* xb = x + (size_t)b * N * F;
    float Qmax = qsb[N - 1];
    float a1 = 0.f, a2 = 0.f, s1 = 0.f, s2 = 0.f;
#pragma unroll
    for (int r = 0; r < RPC; ++r) {
        int t = c * RPC + r;
        float d = qsb[t] - Qmax;
        int id = idb[t];
        float e1 = __expf(d);
        float e2 = __expf(0.2f * d);
        float xv = xb[(size_t)id * F + lane];
        a1 += e1 * xv; s1 += e1;
        a2 += e2 * xv; s2 += e2;
    }
    size_t row = ((size_t)(b * NCH + c)) * NC;
    tot1[row + lane] = a1;
    tot2[row + lane] = a2;
    if (lane == 0) { tot1[row + 64] = s1; tot2[row + 64] = s2; }
}

// ---------------------------------------------------------------------------
// K4: in-place exclusive scans of chunk totals. One wave per (arr,b,comp) job:
// arr0 (tot1): exclusive SUFFIX over chunks; arr1 (tot2): exclusive PREFIX.
// 520 jobs = 130 blocks x 4 waves. Wave scan: 4 elems/lane + shfl_up.
// ---------------------------------------------------------------------------
__global__ __launch_bounds__(256) void scan_kernel(
        float* __restrict__ tot1, float* __restrict__ tot2) {
    int wave = threadIdx.x >> 6, lane = threadIdx.x & 63;
    int job = blockIdx.x * 4 + wave;           // 0..519
    int arr = job >= (BZ * NC);
    int rem = job - arr * (BZ * NC);
    int b = rem / NC, comp = rem % NC;
    float* base = (arr ? tot2 : tot1) + ((size_t)b * NCH) * NC + comp;

    float v[4];
#pragma unroll
    for (int t = 0; t < 4; ++t) {
        int e = lane * 4 + t;
        int c = arr ? e : (NCH - 1 - e);       // suffix scan = reversed prefix
        v[t] = base[(size_t)c * NC];
    }
    float s = v[0] + v[1] + v[2] + v[3];
    float inc = s;
#pragma unroll
    for (int off = 1; off < 64; off <<= 1) {
        float o = __shfl_up(inc, off, 64);
        if (lane >= off) inc += o;
    }
    float exc = inc - s;
    float w[4];
    w[0] = exc; w[1] = w[0] + v[0]; w[2] = w[1] + v[1]; w[3] = w[2] + v[2];
#pragma unroll
    for (int t = 0; t < 4; ++t) {
        int e = lane * 4 + t;
        int c = arr ? e : (NCH - 1 - e);
        base[(size_t)c * NC] = w[t];
    }
}

// ---------------------------------------------------------------------------
// K5: epilogue. grid BZ*64 x 512 (8 waves, 8 rows i each).
// p = p_arr[i]; c = min(p>>4, 255); r0 = p - 16c.
// num/den = c1*(suffix_excl[c] + rows p..16c+15) + c2*(prefix_excl[c] + rows 16c..p-1)
// Exactly 16 x-row gathers per i. LDS transpose -> coalesced out[b][f][i].
// ---------------------------------------------------------------------------
__global__ __launch_bounds__(512) void out_kernel(
        const float* __restrict__ kq, const float* __restrict__ q_sorted,
        const int* __restrict__ id_sorted, const int* __restrict__ p_arr,
        const float* __restrict__ tot1, const float* __restrict__ tot2,
        const float* __restrict__ x, float* __restrict__ out) {
    __shared__ float tile[64 * 65];
    int b = blockIdx.x >> 6;
    int i0 = (blockIdx.x & 63) * 64;
    int wave = threadIdx.x >> 6, lane = threadIdx.x & 63;
    const float* qsb = q_sorted + b * N;
    const int* idb = id_sorted + b * N;
    const float* xb = x + (size_t)b * N * F;
    float Qmax = qsb[N - 1];

    for (int s = 0; s < 8; ++s) {
        int il = wave * 8 + s;
        int i = i0 + il;
        float kk = kq[b * N + i];
        int p = p_arr[b * N + i];
        int c = p >> 4; if (c > NCH - 1) c = NCH - 1;
        int r0 = p - (c << 4);
        float u = kk + Qmax;
        float M = fmaxf(u, 0.2f * u);
        float c1 = __expf(u - M);
        float c2 = __expf(0.2f * u - M);
        size_t row = ((size_t)(b * NCH + c)) * NC;
        float a1 = tot1[row + lane], s1 = tot1[row + 64];
        float a2 = tot2[row + lane], s2 = tot2[row + 64];
        int tb = c << 4;
#pragma unroll
        for (int r = 0; r < RPC; ++r) {
            float d = qsb[tb + r] - Qmax;
            int id = idb[tb + r];
            float xv = xb[(size_t)id * F + lane];
            if (r >= r0) { float e1 = __expf(d);        a1 += e1 * xv; s1 += e1; }
            else         { float e2 = __expf(0.2f * d); a2 += e2 * xv; s2 += e2; }
        }
        float num = c1 * a1 + c2 * a2;
        float den = c1 * s1 + c2 * s2;
        tile[lane * 65 + il] = num / den;
    }
    __syncthreads();
#pragma unroll
    for (int rep = 0; rep < 8; ++rep) {
        int ff = rep * 8 + wave;
        out[((size_t)(b * F + ff)) * N + i0 + lane] = tile[ff * 65 + lane];
    }
}

// ---------------------------------------------------------------------------
extern "C" void kernel_launch(void* const* d_in, const int* in_sizes, int n_in,
                              void* d_out, int out_size, void* d_ws, size_t ws_size,
                              hipStream_t stream) {
    const float* x  = (const float*)d_in[0];
    const float* wk = (const float*)d_in[1];
    const float* wq = (const float*)d_in[2];
    float* out = (float*)d_out;

    // ws layout (floats): kq[2*BZ*N] | q_sorted[BZ*N] | id_sorted[BZ*N] |
    //                     p_arr[BZ*N] | tot1[BZ*NCH*NC] | tot2[BZ*NCH*NC]
    float* ws = (float*)d_ws;
    float* kq       = ws;
    float* q_sorted = ws + 2 * BZ * N;
    int*   id_sorted = (int*)(ws + 3 * BZ * N);
    int*   p_arr     = (int*)(ws + 4 * BZ * N);
    float* tot1     = ws + 5 * BZ * N;
    float* tot2     = tot1 + BZ * NCH * NC;

    kq_kernel<<<BZ * N / 4, 256, 0, stream>>>(x, wk, wq, kq);
    rank_kernel<<<BZ * 64, 1024, 0, stream>>>(kq, q_sorted, id_sorted, p_arr);
    chunk_kernel<<<BZ * 64, 256, 0, stream>>>(x, q_sorted, id_sorted, tot1, tot2);
    scan_kernel<<<130, 256, 0, stream>>>(tot1, tot2);
    out_kernel<<<BZ * 64, 512, 0, stream>>>(kq, q_sorted, id_sorted, p_arr,
                                            tot1, tot2, x, out);
}

// Round 3
// 107.260 us; speedup vs baseline: 2.5446x; 1.3031x over previous
//
#include <hip/hip_runtime.h>

#define N 4096
#define F 64
#define BZ 4
#define NCH 1024         // chunks per batch
#define RPC 4            // sorted rows per chunk
#define NC 65            // 64 features + 1 denominator component

// ---------------------------------------------------------------------------
// K1: k[b][i] = x[b,i,:]·wk ; q[b][i] = x[b,i,:]·wq.  Wave per row.
// ---------------------------------------------------------------------------
__global__ __launch_bounds__(256) void kq_kernel(
        const float* __restrict__ x, const float* __restrict__ wk,
        const float* __restrict__ wq, float* __restrict__ kq) {
    int wave = blockIdx.x * 4 + (threadIdx.x >> 6);
    int lane = threadIdx.x & 63;
    int b = wave >> 12;
    int i = wave & (N - 1);
    float xv = x[((size_t)(b * N + i)) * F + lane];
    float kk = xv * wk[lane];
    float qq = xv * wq[lane];
    for (int off = 32; off > 0; off >>= 1) {
        kk += __shfl_down(kk, off, 64);
        qq += __shfl_down(qq, off, 64);
    }
    if (lane == 0) {
        kq[b * N + i] = kk;            // k block
        kq[BZ * N + b * N + i] = qq;   // q block
    }
}

// ---------------------------------------------------------------------------
// K2: counting rank-sort + split points. grid BZ*64 x 1024.
// float4 LDS reads (ds_read_b128) -> VALU-bound (~67M pair compares total).
//   rank_j = #{s : q_s < q_j  ||  (q_s == q_j && s < j)}
//   p_j    = #{s : q_s < -k_j}
// ---------------------------------------------------------------------------
__global__ __launch_bounds__(1024) void rank_kernel(
        const float* __restrict__ kq, float* __restrict__ q_sorted,
        int* __restrict__ id_sorted, int* __restrict__ p_arr) {
    __shared__ float qs[N];
    __shared__ unsigned short pc[16][64];
    __shared__ unsigned short pc2[16][64];
    int b = blockIdx.x >> 6;
    int tid = threadIdx.x;
    const float* qb = kq + BZ * N + b * N;
    for (int t = tid; t < N; t += 1024) qs[t] = qb[t];
    __syncthreads();

    int jl = tid & 63, part = tid >> 6;
    int j = (blockIdx.x & 63) * 64 + jl;
    float qj = qs[j];
    float theta = -kq[b * N + j];
    int cnt = 0, cnt2 = 0;
    const float4* q4 = (const float4*)qs;
    int s0 = part * 64;                       // float4 units
#pragma unroll 8
    for (int t4 = 0; t4 < 64; ++t4) {
        float4 v = q4[s0 + t4];
        int sb = (s0 + t4) * 4;
        cnt  += (int)((v.x < qj) | ((v.x == qj) & (sb + 0 < j)));
        cnt  += (int)((v.y < qj) | ((v.y == qj) & (sb + 1 < j)));
        cnt  += (int)((v.z < qj) | ((v.z == qj) & (sb + 2 < j)));
        cnt  += (int)((v.w < qj) | ((v.w == qj) & (sb + 3 < j)));
        cnt2 += (int)(v.x < theta) + (int)(v.y < theta)
              + (int)(v.z < theta) + (int)(v.w < theta);
    }
    pc[part][jl] = (unsigned short)cnt;
    pc2[part][jl] = (unsigned short)cnt2;
    __syncthreads();

    if (part == 0) {
        int r = 0, p = 0;
#pragma unroll
        for (int pp = 0; pp < 16; ++pp) { r += pc[pp][jl]; p += pc2[pp][jl]; }
        q_sorted[b * N + r] = qj;
        id_sorted[b * N + r] = j;
        p_arr[b * N + j] = p;
    }
}

// ---------------------------------------------------------------------------
// K3: per-chunk totals, RPC=4. grid BZ*NCH/4 blocks x 256 (wave per chunk).
// ---------------------------------------------------------------------------
__global__ __launch_bounds__(256) void chunk_kernel(
        const float* __restrict__ x, const float* __restrict__ q_sorted,
        const int* __restrict__ id_sorted, float* __restrict__ tot1,
        float* __restrict__ tot2) {
    int wave = threadIdx.x >> 6, lane = threadIdx.x & 63;
    int c = blockIdx.x * 4 + wave;            // global chunk 0..BZ*NCH-1
    int b = c >> 10;
    int cl = c & (NCH - 1);
    const float* qsb = q_sorted + b * N;
    const int* idb = id_sorted + b * N;
    const float* xb = x + (size_t)b * N * F;
    float Qmax = qsb[N - 1];
    float a1 = 0.f, a2 = 0.f, s1 = 0.f, s2 = 0.f;
#pragma unroll
    for (int r = 0; r < RPC; ++r) {
        int t = cl * RPC + r;
        float d = qsb[t] - Qmax;
        int id = idb[t];
        float e1 = __expf(d);
        float e2 = __expf(0.2f * d);
        float xv = xb[(size_t)id * F + lane];
        a1 += e1 * xv; s1 += e1;
        a2 += e2 * xv; s2 += e2;
    }
    size_t row = (size_t)c * NC;
    tot1[row + lane] = a1;
    tot2[row + lane] = a2;
    if (lane == 0) { tot1[row + 64] = s1; tot2[row + 64] = s2; }
}

// ---------------------------------------------------------------------------
// K4: in-place exclusive scans over NCH=1024 chunks. Wave per (arr,b,comp):
// 520 jobs = 130 blocks x 4 waves; 16 elems/lane + shfl_up wave scan.
// arr0 (tot1): exclusive SUFFIX; arr1 (tot2): exclusive PREFIX.
// ---------------------------------------------------------------------------
__global__ __launch_bounds__(256) void scan_kernel(
        float* __restrict__ tot1, float* __restrict__ tot2) {
    int wave = threadIdx.x >> 6, lane = threadIdx.x & 63;
    int job = blockIdx.x * 4 + wave;           // 0..519
    int arr = job >= (BZ * NC);
    int rem = job - arr * (BZ * NC);
    int b = rem / NC, comp = rem % NC;
    float* base = (arr ? tot2 : tot1) + ((size_t)b * NCH) * NC + comp;

    float v[16];
#pragma unroll
    for (int t = 0; t < 16; ++t) {
        int e = lane * 16 + t;
        int c = arr ? e : (NCH - 1 - e);       // suffix scan = reversed prefix
        v[t] = base[(size_t)c * NC];
    }
    float s = 0.f;
#pragma unroll
    for (int t = 0; t < 16; ++t) s += v[t];
    float inc = s;
#pragma unroll
    for (int off = 1; off < 64; off <<= 1) {
        float o = __shfl_up(inc, off, 64);
        if (lane >= off) inc += o;
    }
    float run = inc - s;                       // exclusive across lanes
#pragma unroll
    for (int t = 0; t < 16; ++t) {
        int e = lane * 16 + t;
        int c = arr ? e : (NCH - 1 - e);
        float vv = v[t];
        base[(size_t)c * NC] = run;
        run += vv;
    }
}

// ---------------------------------------------------------------------------
// K5: epilogue. grid BZ*64 x 1024 (16 waves, 4 rows each).
// p = p_arr[i]; c = min(p>>2, NCH-1); r0 = p - 4c; only 4 x-row gathers per i.
// LDS transpose -> coalesced out[b][f][i] stores.
// ---------------------------------------------------------------------------
__global__ __launch_bounds__(1024) void out_kernel(
        const float* __restrict__ kq, const float* __restrict__ q_sorted,
        const int* __restrict__ id_sorted, const int* __restrict__ p_arr,
        const float* __restrict__ tot1, const float* __restrict__ tot2,
        const float* __restrict__ x, float* __restrict__ out) {
    __shared__ float tile[64 * 65];
    int b = blockIdx.x >> 6;
    int i0 = (blockIdx.x & 63) * 64;
    int wave = threadIdx.x >> 6, lane = threadIdx.x & 63;
    const float* qsb = q_sorted + b * N;
    const int* idb = id_sorted + b * N;
    const float* xb = x + (size_t)b * N * F;
    float Qmax = qsb[N - 1];

#pragma unroll
    for (int s = 0; s < 4; ++s) {
        int il = wave * 4 + s;
        int i = i0 + il;
        float kk = kq[b * N + i];
        int p = p_arr[b * N + i];
        int c = p >> 2; if (c > NCH - 1) c = NCH - 1;
        int r0 = p - (c << 2);
        float u = kk + Qmax;
        float M = fmaxf(u, 0.2f * u);
        float c1 = __expf(u - M);
        float c2 = __expf(0.2f * u - M);
        size_t row = ((size_t)(b * NCH + c)) * NC;
        float a1 = tot1[row + lane], s1 = tot1[row + 64];
        float a2 = tot2[row + lane], s2 = tot2[row + 64];
        int tb = c << 2;
#pragma unroll
        for (int r = 0; r < RPC; ++r) {
            float d = qsb[tb + r] - Qmax;
            int id = idb[tb + r];
            float xv = xb[(size_t)id * F + lane];
            if (r >= r0) { float e1 = __expf(d);        a1 += e1 * xv; s1 += e1; }
            else         { float e2 = __expf(0.2f * d); a2 += e2 * xv; s2 += e2; }
        }
        float num = c1 * a1 + c2 * a2;
        float den = c1 * s1 + c2 * s2;
        tile[lane * 65 + il] = num / den;
    }
    __syncthreads();
#pragma unroll
    for (int rep = 0; rep < 4; ++rep) {
        int ff = rep * 16 + wave;
        out[((size_t)(b * F + ff)) * N + i0 + lane] = tile[ff * 65 + lane];
    }
}

// ---------------------------------------------------------------------------
extern "C" void kernel_launch(void* const* d_in, const int* in_sizes, int n_in,
                              void* d_out, int out_size, void* d_ws, size_t ws_size,
                              hipStream_t stream) {
    const float* x  = (const float*)d_in[0];
    const float* wk = (const float*)d_in[1];
    const float* wq = (const float*)d_in[2];
    float* out = (float*)d_out;

    // ws layout (floats): kq[2*BZ*N] | q_sorted[BZ*N] | id_sorted[BZ*N] |
    //                     p_arr[BZ*N] | tot1[BZ*NCH*NC] | tot2[BZ*NCH*NC]
    float* ws = (float*)d_ws;
    float* kq        = ws;
    float* q_sorted  = ws + 2 * BZ * N;
    int*   id_sorted = (int*)(ws + 3 * BZ * N);
    int*   p_arr     = (int*)(ws + 4 * BZ * N);
    float* tot1      = ws + 5 * BZ * N;
    float* tot2      = tot1 + BZ * NCH * NC;

    kq_kernel<<<BZ * N / 4, 256, 0, stream>>>(x, wk, wq, kq);
    rank_kernel<<<BZ * 64, 1024, 0, stream>>>(kq, q_sorted, id_sorted, p_arr);
    chunk_kernel<<<BZ * NCH / 4, 256, 0, stream>>>(x, q_sorted, id_sorted, tot1, tot2);
    scan_kernel<<<130, 256, 0, stream>>>(tot1, tot2);
    out_kernel<<<BZ * 64, 1024, 0, stream>>>(kq, q_sorted, id_sorted, p_arr,
                                             tot1, tot2, x, out);
}